// Round 6
// baseline (1791.102 us; speedup 1.0000x reference)
//
#include <hip/hip_runtime.h>

static constexpr int Bsz = 512;
static constexpr int Tsz = 256;
static constexpr int Nsz = 128;
static constexpr int Msz = 256;

using short8  = __attribute__((ext_vector_type(8))) short;
using ushort8v= __attribute__((ext_vector_type(8))) unsigned short;
using f32x4   = __attribute__((ext_vector_type(4))) float;

__device__ __forceinline__ float rcp_fast(float v){ return __builtin_amdgcn_rcpf(v); }
__device__ __forceinline__ float sigmoid_fast(float v){ return rcp_fast(1.0f + __expf(-v)); }
__device__ __forceinline__ float tanh_fast(float v){ return 1.0f - 2.0f * rcp_fast(1.0f + __expf(2.0f * v)); }
__device__ __forceinline__ unsigned short bf16r(float f){
  unsigned u = __float_as_uint(f);
  u += 0x7FFFu + ((u >> 16) & 1u);
  return (unsigned short)(u >> 16);
}

// ---------------------------------------------------------------------------
// HS layout (unit-interleaved): HS[t][b] = 256 uints; uint[u] = h|s<<16.
// Written sc0 sc1 (write-through to MALL) by k_scan; read sc0 sc1 in-loop.
// Web layout: [u][k] bf16-hi (131072 shorts) then [u][k] bf16-residual —
// transposed so a lane's B-fragment (8 consecutive k, fixed u) is one 16B load.
// ---------------------------------------------------------------------------

// K0: HS slab t=0 + zero scan counters + We -> bf16-hi/res transpose (once).
__global__ __launch_bounds__(256) void k_init(const float* __restrict__ h_in,
                                              const float* __restrict__ s_in,
                                              const float* __restrict__ We,
                                              unsigned short* __restrict__ HS,
                                              int* __restrict__ ctr,
                                              unsigned short* __restrict__ Web){
  const int i = blockIdx.x * 256 + threadIdx.x;   // 0 .. B*M-1 (131072)
  if (i < 8192) ctr[i] = 0;
  const float h = h_in[i];
  const float s = s_in[i];
  const int b = i >> 8;
  const int m = i & 255;
  unsigned* row = (unsigned*)(HS + (size_t)b * 512);
  row[m] = (unsigned)bf16r(h) | ((unsigned)bf16r(s) << 16);
  // We[k][u] (512x256 fp32) -> Web[u][k] hi + residual (block-invariant)
  const int u = i >> 9;        // 0..255
  const int k = i & 511;       // 0..511
  const float wv = We[(size_t)k*256 + u];
  const unsigned short hi = bf16r(wv);
  const float res = wv - __uint_as_float((unsigned)hi << 16);
  Web[(size_t)u*512 + k]          = hi;
  Web[131072 + (size_t)u*512 + k] = bf16r(res);
}

// ---------------------------------------------------------------------------
// K1: Q[b][n][u] = exp( 2 * sum_t x[b][t][n] * Ue[t][u] )   (r2, pre-exp'd)
// ---------------------------------------------------------------------------
__global__ __launch_bounds__(256) void k_r2exp(const float* __restrict__ x,
                                               const float* __restrict__ Ue,
                                               float* __restrict__ Q){
  const int b  = blockIdx.x;
  const int n0 = (blockIdx.y >> 2) * 64;
  const int u0 = (blockIdx.y & 3) * 64;
  __shared__ float Al[16][68];
  __shared__ float Bl[16][68];
  const int tid  = threadIdx.x;
  const int lane = tid & 63;
  const int kq   = tid >> 6;
  const int ty   = tid >> 4;
  const int tx   = tid & 15;
  float acc[4][4] = {};
  const float* xb = x + (size_t)b * Tsz * Nsz;
  for (int k0 = 0; k0 < Tsz; k0 += 16){
    #pragma unroll
    for (int i = 0; i < 4; ++i){
      const int k = kq*4 + i;
      Al[k][lane] = xb[(size_t)(k0+k)*Nsz + n0 + lane];
      Bl[k][lane] = Ue[(size_t)(k0+k)*Tsz + u0 + lane];
    }
    __syncthreads();
    #pragma unroll
    for (int kk = 0; kk < 16; ++kk){
      const float4 a = *(const float4*)&Al[kk][ty*4];
      const float4 w = *(const float4*)&Bl[kk][tx*4];
      const float av[4] = {a.x,a.y,a.z,a.w};
      const float wv[4] = {w.x,w.y,w.z,w.w};
      #pragma unroll
      for (int i=0;i<4;++i)
        #pragma unroll
        for (int j=0;j<4;++j)
          acc[i][j] = fmaf(av[i], wv[j], acc[i][j]);
    }
    __syncthreads();
  }
  float* Qb = Q + (size_t)b * Nsz * Tsz;
  #pragma unroll
  for (int i=0;i<4;++i){
    float4 v;
    v.x = __expf(2.0f*acc[i][0]);
    v.y = __expf(2.0f*acc[i][1]);
    v.z = __expf(2.0f*acc[i][2]);
    v.w = __expf(2.0f*acc[i][3]);
    *(float4*)&Qb[(size_t)(n0 + ty*4 + i)*Tsz + u0 + tx*4] = v;
  }
}

// ---------------------------------------------------------------------------
// K2: persistent LSTM scan, v4 (unchanged — zero cache-maintenance sync;
// sc0 sc1 write-through HS, relaxed flags).
// ---------------------------------------------------------------------------
__global__ __launch_bounds__(256, 1) void k_scan(const float* __restrict__ x,
                                                 const float* __restrict__ Wk,
                                                 const float* __restrict__ Wr,
                                                 const float* __restrict__ bias,
                                                 const float* __restrict__ s_in,
                                                 unsigned short* __restrict__ HS,
                                                 int* __restrict__ ctr){
  const int bgq = blockIdx.x & 31;    // batch group 0..31 (16 batches)
  const int ug  = blockIdx.x >> 5;    // unit group 0..3 (64 units)
  const int b0  = bgq * 16;
  const int u0  = ug * 64;
  const int tid  = threadIdx.x;
  const int w    = tid >> 6;          // wave 0..3 -> units u0+16w..
  const int lane = tid & 63;
  const int nl   = lane & 15;
  const int kq   = lane >> 4;

  __shared__ unsigned short Xa[4*16*32];   // x_t chunks (k=0..127),   4 KB
  __shared__ unsigned short Ha[8*16*32];   // h_t chunks (k=128..383), 8 KB

  const int ucol = u0 + (w<<4) + nl;       // this lane's unit column

  // ---- preload W fragments (bf16) into registers: 12 chunks x 4 gates ----
  short8 wf[12][4];
  #pragma unroll
  for (int c = 0; c < 12; ++c){
    #pragma unroll
    for (int g = 0; g < 4; ++g){
      const int jcol = g*Msz + ucol;
      short8 f;
      #pragma unroll
      for (int j = 0; j < 8; ++j){
        const int k = c*32 + kq*8 + j;
        const float wv = (k < Nsz) ? Wk[(size_t)k*(4*Msz) + jcol]
                                   : Wr[(size_t)(k - Nsz)*(4*Msz) + jcol];
        f[j] = (short)bf16r(wv);
      }
      wf[c][g] = f;
    }
  }

  // ---- per-lane state: 4 batch rows x 1 unit ----
  const int r0 = kq*4;                     // first of 4 batch rows (C layout)
  float bi[4];
  #pragma unroll
  for (int g = 0; g < 4; ++g) bi[g] = bias[g*Msz + ucol];
  float s_reg[4];
  #pragma unroll
  for (int r = 0; r < 4; ++r)
    s_reg[r] = s_in[(size_t)(b0 + r0 + r)*Msz + ucol];

  // staging indices (256 threads cover 16 rows x full width)
  const int srow = tid >> 4;               // 0..15
  const int sx_n = (tid & 15) * 8;         // x col base (8 fp32)
  const int sh_m = (tid & 15) * 16;        // h col base (16 units)
  const int arow = nl*32 + kq*8;           // A-fragment LDS offset (shorts)

  #pragma unroll 1
  for (int t = 0; t < Tsz - 1; ++t){
    // ---- stage x_t (no dependence on the group barrier) ----
    {
      const float* xp = x + ((size_t)(b0+srow)*Tsz + t)*Nsz + sx_n;
      const float4 v0 = *(const float4*)(xp);
      const float4 v1 = *(const float4*)(xp + 4);
      ushort4 o0, o1;
      o0.x = bf16r(v0.x); o0.y = bf16r(v0.y); o0.z = bf16r(v0.z); o0.w = bf16r(v0.w);
      o1.x = bf16r(v1.x); o1.y = bf16r(v1.y); o1.z = bf16r(v1.z); o1.w = bf16r(v1.w);
      const int base = (sx_n>>5)*512 + srow*32 + (sx_n & 31);
      *(ushort4*)&Xa[base]     = o0;
      *(ushort4*)&Xa[base + 4] = o1;
    }
    __syncthreads();   // Xa ready

    // ---- x_t @ Wk : chunks 0..3 (overlaps producers still finishing h_t) ----
    f32x4 acc0 = {0.f,0.f,0.f,0.f}, acc1 = {0.f,0.f,0.f,0.f};
    f32x4 acc2 = {0.f,0.f,0.f,0.f}, acc3 = {0.f,0.f,0.f,0.f};
    #pragma unroll
    for (int c = 0; c < 4; ++c){
      const short8 af = *(const short8*)&Xa[c*512 + arow];
      acc0 = __builtin_amdgcn_mfma_f32_16x16x32_bf16(af, wf[c][0], acc0, 0, 0, 0);
      acc1 = __builtin_amdgcn_mfma_f32_16x16x32_bf16(af, wf[c][1], acc1, 0, 0, 0);
      acc2 = __builtin_amdgcn_mfma_f32_16x16x32_bf16(af, wf[c][2], acc2, 0, 0, 0);
      acc3 = __builtin_amdgcn_mfma_f32_16x16x32_bf16(af, wf[c][3], acc3, 0, 0, 0);
    }

    // ---- wait for h_t: tid0 relaxed spin (no cache ops), then barrier ----
    if (t > 0){
      if (tid == 0){
        int* cp = &ctr[(t-1)*32 + bgq];
        while (__hip_atomic_load(cp, __ATOMIC_RELAXED, __HIP_MEMORY_SCOPE_AGENT) < 4)
          __builtin_amdgcn_s_sleep(1);
      }
      __syncthreads();
    }

    // ---- stage h_t: sc0 sc1 loads (MALL-coherent), extract h (low16) ----
    {
      const unsigned* hp = (const unsigned*)(HS + ((size_t)t*Bsz + b0 + srow)*512) + sh_m;
      uint4 a0, a1, a2, a3;
      asm volatile(
        "global_load_dwordx4 %0, %4, off sc0 sc1\n\t"
        "global_load_dwordx4 %1, %4, off offset:16 sc0 sc1\n\t"
        "global_load_dwordx4 %2, %4, off offset:32 sc0 sc1\n\t"
        "global_load_dwordx4 %3, %4, off offset:48 sc0 sc1\n\t"
        "s_waitcnt vmcnt(0)"
        : "=&v"(a0), "=&v"(a1), "=&v"(a2), "=&v"(a3)
        : "v"(hp)
        : "memory");
      ushort4 h0, h1, h2, h3;
      h0.x=(unsigned short)a0.x; h0.y=(unsigned short)a0.y; h0.z=(unsigned short)a0.z; h0.w=(unsigned short)a0.w;
      h1.x=(unsigned short)a1.x; h1.y=(unsigned short)a1.y; h1.z=(unsigned short)a1.z; h1.w=(unsigned short)a1.w;
      h2.x=(unsigned short)a2.x; h2.y=(unsigned short)a2.y; h2.z=(unsigned short)a2.z; h2.w=(unsigned short)a2.w;
      h3.x=(unsigned short)a3.x; h3.y=(unsigned short)a3.y; h3.z=(unsigned short)a3.z; h3.w=(unsigned short)a3.w;
      const int base = (sh_m>>5)*512 + srow*32 + (sh_m & 31);
      *(ushort4*)&Ha[base +  0] = h0;
      *(ushort4*)&Ha[base +  4] = h1;
      *(ushort4*)&Ha[base +  8] = h2;
      *(ushort4*)&Ha[base + 12] = h3;
    }
    __syncthreads();   // Ha ready

    // ---- h_t @ Wr : chunks 4..11 ----
    #pragma unroll
    for (int c = 0; c < 8; ++c){
      const short8 af = *(const short8*)&Ha[c*512 + arow];
      acc0 = __builtin_amdgcn_mfma_f32_16x16x32_bf16(af, wf[c+4][0], acc0, 0, 0, 0);
      acc1 = __builtin_amdgcn_mfma_f32_16x16x32_bf16(af, wf[c+4][1], acc1, 0, 0, 0);
      acc2 = __builtin_amdgcn_mfma_f32_16x16x32_bf16(af, wf[c+4][2], acc2, 0, 0, 0);
      acc3 = __builtin_amdgcn_mfma_f32_16x16x32_bf16(af, wf[c+4][3], acc3, 0, 0, 0);
    }

    // ---- gate update; pack (h,s) per unit; sc0 sc1 write-through stores ----
    {
      unsigned hv[4];
      #pragma unroll
      for (int r = 0; r < 4; ++r){
        const float ig = sigmoid_fast(acc0[r] + bi[0]);
        const float fg = sigmoid_fast(acc1[r] + bi[1]);
        const float gg = tanh_fast  (acc2[r] + bi[2]);
        const float og = sigmoid_fast(acc3[r] + bi[3]);
        const float s1 = fmaf(fg, s_reg[r], ig * gg);
        s_reg[r] = s1;
        const float hn = og * tanh_fast(s1);
        hv[r] = (unsigned)bf16r(hn) | ((unsigned)bf16r(s1) << 16);
      }
      unsigned* gp = (unsigned*)(HS + ((size_t)(t+1)*Bsz + b0 + r0)*512) + ucol;
      asm volatile(
        "global_store_dword %0, %1, off sc0 sc1\n\t"
        "global_store_dword %0, %2, off offset:1024 sc0 sc1\n\t"
        "global_store_dword %0, %3, off offset:2048 sc0 sc1\n\t"
        "global_store_dword %0, %4, off offset:3072 sc0 sc1\n\t"
        "s_waitcnt vmcnt(0)"
        :: "v"(gp), "v"(hv[0]), "v"(hv[1]), "v"(hv[2]), "v"(hv[3])
        : "memory");
    }

    // ---- publish: stores already at MALL -> relaxed flag add ----
    __syncthreads();
    if (tid == 0)
      __hip_atomic_fetch_add(&ctr[t*32 + bgq], 1, __ATOMIC_RELAXED,
                             __HIP_MEMORY_SCOPE_AGENT);
  }
}

// ---------------------------------------------------------------------------
// K3: attention v4 — MFMA r1 with PRECOMPUTED Web (bf16-hi + residual, [u][k]
// transposed: lane's B-fragment = one contiguous 16B L2-resident load).
// The per-block We conversion (~430 us chip-wide VALU) is gone.
// ---------------------------------------------------------------------------
__global__ __launch_bounds__(256, 4) void k_attn(const unsigned short* __restrict__ HS,
                                              const float* __restrict__ Q,
                                              const unsigned short* __restrict__ Web,
                                              const float* __restrict__ ve,
                                              const float* __restrict__ x,
                                              float* __restrict__ out){
  const unsigned wgid = blockIdx.x + (blockIdx.y << 9);
  const unsigned l    = ((wgid & 7u) << 10) + (wgid >> 3);
  const int b  = (int)(l >> 4);
  const int t0 = (int)(l & 15u) << 4;

  __shared__ __align__(16) char smem[36096];
  float* Pl  = (float*)smem;               // [16][260] fp32
  char*  Ab  = smem + 16640;               // Al: [16][512] bf16 swizzled (phase 1)
  float* Qu  = (float*)(smem + 16640);     // [128][36] fp32 (phase 2, aliases Al)
  float* vel = (float*)(smem + 35072);     // [256]

  const int tid = threadIdx.x;
  vel[tid] = ve[tid];

  // ---- stage packed HS -> Al bf16 [16][512], XOR-swizzle ((row&7)<<4) ----
  {
    const int row = tid >> 4;
    const int seg = tid & 15;
    const uint4* src = (const uint4*)((const unsigned*)(HS + ((size_t)(t0 + row)*Bsz + b)*512) + seg*16);
    const uint4 q0 = src[0], q1 = src[1], q2 = src[2], q3 = src[3];
    ushort8v h0 = {(unsigned short)q0.x,(unsigned short)q0.y,(unsigned short)q0.z,(unsigned short)q0.w,
                   (unsigned short)q1.x,(unsigned short)q1.y,(unsigned short)q1.z,(unsigned short)q1.w};
    ushort8v h1 = {(unsigned short)q2.x,(unsigned short)q2.y,(unsigned short)q2.z,(unsigned short)q2.w,
                   (unsigned short)q3.x,(unsigned short)q3.y,(unsigned short)q3.z,(unsigned short)q3.w};
    ushort8v s0 = {(unsigned short)(q0.x>>16),(unsigned short)(q0.y>>16),(unsigned short)(q0.z>>16),(unsigned short)(q0.w>>16),
                   (unsigned short)(q1.x>>16),(unsigned short)(q1.y>>16),(unsigned short)(q1.z>>16),(unsigned short)(q1.w>>16)};
    ushort8v s1 = {(unsigned short)(q2.x>>16),(unsigned short)(q2.y>>16),(unsigned short)(q2.z>>16),(unsigned short)(q2.w>>16),
                   (unsigned short)(q3.x>>16),(unsigned short)(q3.y>>16),(unsigned short)(q3.z>>16),(unsigned short)(q3.w>>16)};
    const int sw = (row & 7) << 4;
    const int hb = row*1024 + seg*32;      // logical byte of h-part
    *(ushort8v*)(Ab + ((hb      ) ^ sw)) = h0;
    *(ushort8v*)(Ab + ((hb + 16 ) ^ sw)) = h1;
    *(ushort8v*)(Ab + ((hb + 512) ^ sw)) = s0;
    *(ushort8v*)(Ab + ((hb + 528) ^ sw)) = s1;
  }
  __syncthreads();

  // ---- r1 via MFMA: wave w owns u in [w*64, w*64+64) ----
  {
    const int lane = tid & 63;
    const int w    = tid >> 6;
    const int nl16 = lane & 15;            // = A row (t), = B col (u_local)
    const int kq   = lane >> 4;
    f32x4 acc[4];
    #pragma unroll
    for (int nt = 0; nt < 4; ++nt) acc[nt] = (f32x4){0.f,0.f,0.f,0.f};
    const int aswz = (nl16 & 7) << 4;
    const unsigned short* wb = Web + (size_t)(w*64 + nl16)*512 + kq*8;
    #pragma unroll 2
    for (int kc = 0; kc < 16; ++kc){
      const short8 af = *(const short8*)(Ab + ((nl16*1024 + kc*64 + kq*16) ^ aswz));
      #pragma unroll
      for (int nt = 0; nt < 4; ++nt){
        const short8 b1 = *(const short8*)(wb + (size_t)nt*8192 + kc*32);
        const short8 b2 = *(const short8*)(wb + 131072 + (size_t)nt*8192 + kc*32);
        acc[nt] = __builtin_amdgcn_mfma_f32_16x16x32_bf16(af, b1, acc[nt], 0, 0, 0);
        acc[nt] = __builtin_amdgcn_mfma_f32_16x16x32_bf16(af, b2, acc[nt], 0, 0, 0);
      }
    }
    // D layout: col = lane&15 (u_local), row = (lane>>4)*4 + r (t)
    #pragma unroll
    for (int nt = 0; nt < 4; ++nt)
      #pragma unroll
      for (int r = 0; r < 4; ++r)
        Pl[(kq*4 + r)*260 + w*64 + nt*16 + nl16] = __expf(2.0f*acc[nt][r]);
  }

  // ---- e-loop: thread tile = t rows {2tt, 2tt+1} x n cols {tn + 32r} ----
  const int tt = tid >> 5;                 // 0..7
  const int tn = tid & 31;                 // 0..31
  float acc[2][4] = {};
  const float* Qb = Q + (size_t)b * Nsz * Tsz;

  for (int u0 = 0; u0 < Tsz; u0 += 32){
    __syncthreads();                       // prior readers of region done
    #pragma unroll
    for (int i2 = 0; i2 < 4; ++i2){
      const int seg = i2*256 + tid;        // 0..1023
      const int row = seg >> 3;            // 0..127
      const int q   = seg & 7;             // 0..7
      *(float4*)&Qu[row*36 + q*4] = *(const float4*)&Qb[row*256 + u0 + q*4];
    }
    __syncthreads();
    #pragma unroll
    for (int us = 0; us < 8; ++us){
      const int uu = u0 + us*4;
      const float4 ve4 = *(const float4*)&vel[uu];
      const float4 p0  = *(const float4*)&Pl[(2*tt+0)*260 + uu];
      const float4 p1  = *(const float4*)&Pl[(2*tt+1)*260 + uu];
      #pragma unroll
      for (int r = 0; r < 4; ++r){
        const float4 qv = *(const float4*)&Qu[(tn + 32*r)*36 + us*4];
        acc[0][r] = fmaf(ve4.x, rcp_fast(fmaf(p0.x, qv.x, 1.0f)), acc[0][r]);
        acc[0][r] = fmaf(ve4.y, rcp_fast(fmaf(p0.y, qv.y, 1.0f)), acc[0][r]);
        acc[0][r] = fmaf(ve4.z, rcp_fast(fmaf(p0.z, qv.z, 1.0f)), acc[0][r]);
        acc[0][r] = fmaf(ve4.w, rcp_fast(fmaf(p0.w, qv.w, 1.0f)), acc[0][r]);
        acc[1][r] = fmaf(ve4.x, rcp_fast(fmaf(p1.x, qv.x, 1.0f)), acc[1][r]);
        acc[1][r] = fmaf(ve4.y, rcp_fast(fmaf(p1.y, qv.y, 1.0f)), acc[1][r]);
        acc[1][r] = fmaf(ve4.z, rcp_fast(fmaf(p1.z, qv.z, 1.0f)), acc[1][r]);
        acc[1][r] = fmaf(ve4.w, rcp_fast(fmaf(p1.w, qv.w, 1.0f)), acc[1][r]);
      }
    }
  }

  // ---- softmax in registers (row t in one 32-lane group) ----
  float ex[2][4];
  float m0 = -3.0e38f, m1 = -3.0e38f;
  #pragma unroll
  for (int r = 0; r < 4; ++r){
    ex[0][r] = -2.0f * acc[0][r];
    ex[1][r] = -2.0f * acc[1][r];
    m0 = fmaxf(m0, ex[0][r]);
    m1 = fmaxf(m1, ex[1][r]);
  }
  #pragma unroll
  for (int mk = 16; mk >= 1; mk >>= 1){
    m0 = fmaxf(m0, __shfl_xor(m0, mk, 64));
    m1 = fmaxf(m1, __shfl_xor(m1, mk, 64));
  }
  float s0 = 0.0f, s1 = 0.0f;
  #pragma unroll
  for (int r = 0; r < 4; ++r){
    const float p0 = __expf(ex[0][r] - m0);
    const float p1 = __expf(ex[1][r] - m1);
    ex[0][r] = p0; ex[1][r] = p1;
    s0 += p0; s1 += p1;
  }
  #pragma unroll
  for (int mk = 16; mk >= 1; mk >>= 1){
    s0 += __shfl_xor(s0, mk, 64);
    s1 += __shfl_xor(s1, mk, 64);
  }
  const float inv0 = rcp_fast(s0);
  const float inv1 = rcp_fast(s1);

  #pragma unroll
  for (int r = 0; r < 4; ++r){
    const size_t i0 = ((size_t)b*Tsz + t0 + 2*tt + 0)*Nsz + tn + 32*r;
    const size_t i1 = ((size_t)b*Tsz + t0 + 2*tt + 1)*Nsz + tn + 32*r;
    out[i0] = ex[0][r] * inv0 * x[i0];
    out[i1] = ex[1][r] * inv1 * x[i1];
  }
}

// ---------------------------------------------------------------------------
extern "C" void kernel_launch(void* const* d_in, const int* in_sizes, int n_in,
                              void* d_out, int out_size, void* d_ws, size_t ws_size,
                              hipStream_t stream){
  const float* x    = (const float*)d_in[0];
  const float* s_in = (const float*)d_in[1];
  const float* h_in = (const float*)d_in[2];
  const float* We   = (const float*)d_in[3];
  const float* Ue   = (const float*)d_in[4];
  const float* ve   = (const float*)d_in[5];
  const float* Wk   = (const float*)d_in[6];
  const float* Wr   = (const float*)d_in[7];
  const float* bias = (const float*)d_in[8];
  float* out = (float*)d_out;

  // ws layout (~201.9 MB): Q fp32 67MB | HS 134MB | ctr 32KB | Web 512KB
  float* Q = (float*)d_ws;
  unsigned short* HS = (unsigned short*)(Q + (size_t)Bsz*Nsz*Tsz);
  int* ctr = (int*)(HS + (size_t)Tsz*Bsz*512);
  unsigned short* Web = (unsigned short*)(ctr + 8192);

  k_init<<<(Bsz*Msz)/256, 256, 0, stream>>>(h_in, s_in, We, HS, ctr, Web);
  k_r2exp<<<dim3(Bsz, 8), 256, 0, stream>>>(x, Ue, Q);
  k_scan<<<128, 256, 0, stream>>>(x, Wk, Wr, bias, s_in, HS, ctr);
  k_attn<<<dim3(Bsz, Tsz/16), 256, 0, stream>>>(HS, Q, Web, ve, x, out);
}

// Round 7
// 1602.460 us; speedup vs baseline: 1.1177x; 1.1177x over previous
//
#include <hip/hip_runtime.h>

static constexpr int Bsz = 512;
static constexpr int Tsz = 256;
static constexpr int Nsz = 128;
static constexpr int Msz = 256;

using short8  = __attribute__((ext_vector_type(8))) short;
using ushort8v= __attribute__((ext_vector_type(8))) unsigned short;
using f32x4   = __attribute__((ext_vector_type(4))) float;

__device__ __forceinline__ float rcp_fast(float v){ return __builtin_amdgcn_rcpf(v); }
__device__ __forceinline__ float sigmoid_fast(float v){ return rcp_fast(1.0f + __expf(-v)); }
__device__ __forceinline__ float tanh_fast(float v){ return 1.0f - 2.0f * rcp_fast(1.0f + __expf(2.0f * v)); }
__device__ __forceinline__ unsigned short bf16r(float f){
  unsigned u = __float_as_uint(f);
  u += 0x7FFFu + ((u >> 16) & 1u);
  return (unsigned short)(u >> 16);
}

// ---------------------------------------------------------------------------
// HS layout (unit-interleaved): HS[t][b] = 256 uints; uint[u] = h|s<<16.
// Written sc0 sc1 (write-through to MALL) by k_scan; read sc0 sc1 in-loop.
// Web layout (FRAGMENT-MAJOR, fixes R6's scattered loads):
//   idx(kc,w,nt,lane,j) = kc*8192 + w*2048 + nt*512 + lane*8 + j
//   value = bf16hi(We[kc*32 + (lane>>4)*8 + j][w*64 + nt*16 + (lane&15)])
//   residual table at +131072 shorts. A wave's B-fragment load is then
//   base + lane*16B: ONE coalesced 1KB transaction (L2-resident).
// ---------------------------------------------------------------------------

// K0: HS slab t=0 + zero scan counters + We -> fragment-major bf16-hi/res.
__global__ __launch_bounds__(256) void k_init(const float* __restrict__ h_in,
                                              const float* __restrict__ s_in,
                                              const float* __restrict__ We,
                                              unsigned short* __restrict__ HS,
                                              int* __restrict__ ctr,
                                              unsigned short* __restrict__ Web){
  const int i = blockIdx.x * 256 + threadIdx.x;   // 0 .. B*M-1 (131072)
  if (i < 8192) ctr[i] = 0;
  const float h = h_in[i];
  const float s = s_in[i];
  const int b = i >> 8;
  const int m = i & 255;
  unsigned* row = (unsigned*)(HS + (size_t)b * 512);
  row[m] = (unsigned)bf16r(h) | ((unsigned)bf16r(s) << 16);
  // dest-major Wf build: coalesced writes, gather-reads from L2-cached We
  const int j    = i & 7;
  const int lane = (i >> 3) & 63;
  const int nt   = (i >> 9) & 3;
  const int w    = (i >> 11) & 3;
  const int kc   = (i >> 13) & 15;
  const int kq   = lane >> 4;
  const int nl16 = lane & 15;
  const int k = kc*32 + kq*8 + j;          // 0..511
  const int u = w*64 + nt*16 + nl16;       // 0..255
  const float wv = We[(size_t)k*256 + u];
  const unsigned short hi = bf16r(wv);
  const float res = wv - __uint_as_float((unsigned)hi << 16);
  Web[i]          = hi;
  Web[131072 + i] = bf16r(res);
}

// ---------------------------------------------------------------------------
// K1: Q[b][n][u] = exp( 2 * sum_t x[b][t][n] * Ue[t][u] )   (r2, pre-exp'd)
// ---------------------------------------------------------------------------
__global__ __launch_bounds__(256) void k_r2exp(const float* __restrict__ x,
                                               const float* __restrict__ Ue,
                                               float* __restrict__ Q){
  const int b  = blockIdx.x;
  const int n0 = (blockIdx.y >> 2) * 64;
  const int u0 = (blockIdx.y & 3) * 64;
  __shared__ float Al[16][68];
  __shared__ float Bl[16][68];
  const int tid  = threadIdx.x;
  const int lane = tid & 63;
  const int kq   = tid >> 6;
  const int ty   = tid >> 4;
  const int tx   = tid & 15;
  float acc[4][4] = {};
  const float* xb = x + (size_t)b * Tsz * Nsz;
  for (int k0 = 0; k0 < Tsz; k0 += 16){
    #pragma unroll
    for (int i = 0; i < 4; ++i){
      const int k = kq*4 + i;
      Al[k][lane] = xb[(size_t)(k0+k)*Nsz + n0 + lane];
      Bl[k][lane] = Ue[(size_t)(k0+k)*Tsz + u0 + lane];
    }
    __syncthreads();
    #pragma unroll
    for (int kk = 0; kk < 16; ++kk){
      const float4 a = *(const float4*)&Al[kk][ty*4];
      const float4 w = *(const float4*)&Bl[kk][tx*4];
      const float av[4] = {a.x,a.y,a.z,a.w};
      const float wv[4] = {w.x,w.y,w.z,w.w};
      #pragma unroll
      for (int i=0;i<4;++i)
        #pragma unroll
        for (int j=0;j<4;++j)
          acc[i][j] = fmaf(av[i], wv[j], acc[i][j]);
    }
    __syncthreads();
  }
  float* Qb = Q + (size_t)b * Nsz * Tsz;
  #pragma unroll
  for (int i=0;i<4;++i){
    float4 v;
    v.x = __expf(2.0f*acc[i][0]);
    v.y = __expf(2.0f*acc[i][1]);
    v.z = __expf(2.0f*acc[i][2]);
    v.w = __expf(2.0f*acc[i][3]);
    *(float4*)&Qb[(size_t)(n0 + ty*4 + i)*Tsz + u0 + tx*4] = v;
  }
}

// ---------------------------------------------------------------------------
// K2: persistent LSTM scan, v4 (unchanged — zero cache-maintenance sync;
// sc0 sc1 write-through HS, relaxed flags).
// ---------------------------------------------------------------------------
__global__ __launch_bounds__(256, 1) void k_scan(const float* __restrict__ x,
                                                 const float* __restrict__ Wk,
                                                 const float* __restrict__ Wr,
                                                 const float* __restrict__ bias,
                                                 const float* __restrict__ s_in,
                                                 unsigned short* __restrict__ HS,
                                                 int* __restrict__ ctr){
  const int bgq = blockIdx.x & 31;    // batch group 0..31 (16 batches)
  const int ug  = blockIdx.x >> 5;    // unit group 0..3 (64 units)
  const int b0  = bgq * 16;
  const int u0  = ug * 64;
  const int tid  = threadIdx.x;
  const int w    = tid >> 6;          // wave 0..3 -> units u0+16w..
  const int lane = tid & 63;
  const int nl   = lane & 15;
  const int kq   = lane >> 4;

  __shared__ unsigned short Xa[4*16*32];   // x_t chunks (k=0..127),   4 KB
  __shared__ unsigned short Ha[8*16*32];   // h_t chunks (k=128..383), 8 KB

  const int ucol = u0 + (w<<4) + nl;       // this lane's unit column

  // ---- preload W fragments (bf16) into registers: 12 chunks x 4 gates ----
  short8 wf[12][4];
  #pragma unroll
  for (int c = 0; c < 12; ++c){
    #pragma unroll
    for (int g = 0; g < 4; ++g){
      const int jcol = g*Msz + ucol;
      short8 f;
      #pragma unroll
      for (int j = 0; j < 8; ++j){
        const int k = c*32 + kq*8 + j;
        const float wv = (k < Nsz) ? Wk[(size_t)k*(4*Msz) + jcol]
                                   : Wr[(size_t)(k - Nsz)*(4*Msz) + jcol];
        f[j] = (short)bf16r(wv);
      }
      wf[c][g] = f;
    }
  }

  // ---- per-lane state: 4 batch rows x 1 unit ----
  const int r0 = kq*4;                     // first of 4 batch rows (C layout)
  float bi[4];
  #pragma unroll
  for (int g = 0; g < 4; ++g) bi[g] = bias[g*Msz + ucol];
  float s_reg[4];
  #pragma unroll
  for (int r = 0; r < 4; ++r)
    s_reg[r] = s_in[(size_t)(b0 + r0 + r)*Msz + ucol];

  // staging indices (256 threads cover 16 rows x full width)
  const int srow = tid >> 4;               // 0..15
  const int sx_n = (tid & 15) * 8;         // x col base (8 fp32)
  const int sh_m = (tid & 15) * 16;        // h col base (16 units)
  const int arow = nl*32 + kq*8;           // A-fragment LDS offset (shorts)

  #pragma unroll 1
  for (int t = 0; t < Tsz - 1; ++t){
    // ---- stage x_t (no dependence on the group barrier) ----
    {
      const float* xp = x + ((size_t)(b0+srow)*Tsz + t)*Nsz + sx_n;
      const float4 v0 = *(const float4*)(xp);
      const float4 v1 = *(const float4*)(xp + 4);
      ushort4 o0, o1;
      o0.x = bf16r(v0.x); o0.y = bf16r(v0.y); o0.z = bf16r(v0.z); o0.w = bf16r(v0.w);
      o1.x = bf16r(v1.x); o1.y = bf16r(v1.y); o1.z = bf16r(v1.z); o1.w = bf16r(v1.w);
      const int base = (sx_n>>5)*512 + srow*32 + (sx_n & 31);
      *(ushort4*)&Xa[base]     = o0;
      *(ushort4*)&Xa[base + 4] = o1;
    }
    __syncthreads();   // Xa ready

    // ---- x_t @ Wk : chunks 0..3 (overlaps producers still finishing h_t) ----
    f32x4 acc0 = {0.f,0.f,0.f,0.f}, acc1 = {0.f,0.f,0.f,0.f};
    f32x4 acc2 = {0.f,0.f,0.f,0.f}, acc3 = {0.f,0.f,0.f,0.f};
    #pragma unroll
    for (int c = 0; c < 4; ++c){
      const short8 af = *(const short8*)&Xa[c*512 + arow];
      acc0 = __builtin_amdgcn_mfma_f32_16x16x32_bf16(af, wf[c][0], acc0, 0, 0, 0);
      acc1 = __builtin_amdgcn_mfma_f32_16x16x32_bf16(af, wf[c][1], acc1, 0, 0, 0);
      acc2 = __builtin_amdgcn_mfma_f32_16x16x32_bf16(af, wf[c][2], acc2, 0, 0, 0);
      acc3 = __builtin_amdgcn_mfma_f32_16x16x32_bf16(af, wf[c][3], acc3, 0, 0, 0);
    }

    // ---- wait for h_t: tid0 relaxed spin (no cache ops), then barrier ----
    if (t > 0){
      if (tid == 0){
        int* cp = &ctr[(t-1)*32 + bgq];
        while (__hip_atomic_load(cp, __ATOMIC_RELAXED, __HIP_MEMORY_SCOPE_AGENT) < 4)
          __builtin_amdgcn_s_sleep(1);
      }
      __syncthreads();
    }

    // ---- stage h_t: sc0 sc1 loads (MALL-coherent), extract h (low16) ----
    {
      const unsigned* hp = (const unsigned*)(HS + ((size_t)t*Bsz + b0 + srow)*512) + sh_m;
      uint4 a0, a1, a2, a3;
      asm volatile(
        "global_load_dwordx4 %0, %4, off sc0 sc1\n\t"
        "global_load_dwordx4 %1, %4, off offset:16 sc0 sc1\n\t"
        "global_load_dwordx4 %2, %4, off offset:32 sc0 sc1\n\t"
        "global_load_dwordx4 %3, %4, off offset:48 sc0 sc1\n\t"
        "s_waitcnt vmcnt(0)"
        : "=&v"(a0), "=&v"(a1), "=&v"(a2), "=&v"(a3)
        : "v"(hp)
        : "memory");
      ushort4 h0, h1, h2, h3;
      h0.x=(unsigned short)a0.x; h0.y=(unsigned short)a0.y; h0.z=(unsigned short)a0.z; h0.w=(unsigned short)a0.w;
      h1.x=(unsigned short)a1.x; h1.y=(unsigned short)a1.y; h1.z=(unsigned short)a1.z; h1.w=(unsigned short)a1.w;
      h2.x=(unsigned short)a2.x; h2.y=(unsigned short)a2.y; h2.z=(unsigned short)a2.z; h2.w=(unsigned short)a2.w;
      h3.x=(unsigned short)a3.x; h3.y=(unsigned short)a3.y; h3.z=(unsigned short)a3.z; h3.w=(unsigned short)a3.w;
      const int base = (sh_m>>5)*512 + srow*32 + (sh_m & 31);
      *(ushort4*)&Ha[base +  0] = h0;
      *(ushort4*)&Ha[base +  4] = h1;
      *(ushort4*)&Ha[base +  8] = h2;
      *(ushort4*)&Ha[base + 12] = h3;
    }
    __syncthreads();   // Ha ready

    // ---- h_t @ Wr : chunks 4..11 ----
    #pragma unroll
    for (int c = 0; c < 8; ++c){
      const short8 af = *(const short8*)&Ha[c*512 + arow];
      acc0 = __builtin_amdgcn_mfma_f32_16x16x32_bf16(af, wf[c+4][0], acc0, 0, 0, 0);
      acc1 = __builtin_amdgcn_mfma_f32_16x16x32_bf16(af, wf[c+4][1], acc1, 0, 0, 0);
      acc2 = __builtin_amdgcn_mfma_f32_16x16x32_bf16(af, wf[c+4][2], acc2, 0, 0, 0);
      acc3 = __builtin_amdgcn_mfma_f32_16x16x32_bf16(af, wf[c+4][3], acc3, 0, 0, 0);
    }

    // ---- gate update; pack (h,s) per unit; sc0 sc1 write-through stores ----
    {
      unsigned hv[4];
      #pragma unroll
      for (int r = 0; r < 4; ++r){
        const float ig = sigmoid_fast(acc0[r] + bi[0]);
        const float fg = sigmoid_fast(acc1[r] + bi[1]);
        const float gg = tanh_fast  (acc2[r] + bi[2]);
        const float og = sigmoid_fast(acc3[r] + bi[3]);
        const float s1 = fmaf(fg, s_reg[r], ig * gg);
        s_reg[r] = s1;
        const float hn = og * tanh_fast(s1);
        hv[r] = (unsigned)bf16r(hn) | ((unsigned)bf16r(s1) << 16);
      }
      unsigned* gp = (unsigned*)(HS + ((size_t)(t+1)*Bsz + b0 + r0)*512) + ucol;
      asm volatile(
        "global_store_dword %0, %1, off sc0 sc1\n\t"
        "global_store_dword %0, %2, off offset:1024 sc0 sc1\n\t"
        "global_store_dword %0, %3, off offset:2048 sc0 sc1\n\t"
        "global_store_dword %0, %4, off offset:3072 sc0 sc1\n\t"
        "s_waitcnt vmcnt(0)"
        :: "v"(gp), "v"(hv[0]), "v"(hv[1]), "v"(hv[2]), "v"(hv[3])
        : "memory");
    }

    // ---- publish: stores already at MALL -> relaxed flag add ----
    __syncthreads();
    if (tid == 0)
      __hip_atomic_fetch_add(&ctr[t*32 + bgq], 1, __ATOMIC_RELAXED,
                             __HIP_MEMORY_SCOPE_AGENT);
  }
}

// ---------------------------------------------------------------------------
// K3: attention v5 — MFMA r1 with FRAGMENT-MAJOR Web: each wave's B-fragment
// load is base + lane*16B = one coalesced 1KB transaction (L2-resident).
// Loads grouped before MFMAs per kc for ILP; unroll 2 over kc.
// ---------------------------------------------------------------------------
__global__ __launch_bounds__(256, 4) void k_attn(const unsigned short* __restrict__ HS,
                                              const float* __restrict__ Q,
                                              const unsigned short* __restrict__ Web,
                                              const float* __restrict__ ve,
                                              const float* __restrict__ x,
                                              float* __restrict__ out){
  const unsigned wgid = blockIdx.x + (blockIdx.y << 9);
  const unsigned l    = ((wgid & 7u) << 10) + (wgid >> 3);
  const int b  = (int)(l >> 4);
  const int t0 = (int)(l & 15u) << 4;

  __shared__ __align__(16) char smem[36096];
  float* Pl  = (float*)smem;               // [16][260] fp32
  char*  Ab  = smem + 16640;               // Al: [16][512] bf16 swizzled (phase 1)
  float* Qu  = (float*)(smem + 16640);     // [128][36] fp32 (phase 2, aliases Al)
  float* vel = (float*)(smem + 35072);     // [256]

  const int tid = threadIdx.x;
  vel[tid] = ve[tid];

  // ---- stage packed HS -> Al bf16 [16][512], XOR-swizzle ((row&7)<<4) ----
  {
    const int row = tid >> 4;
    const int seg = tid & 15;
    const uint4* src = (const uint4*)((const unsigned*)(HS + ((size_t)(t0 + row)*Bsz + b)*512) + seg*16);
    const uint4 q0 = src[0], q1 = src[1], q2 = src[2], q3 = src[3];
    ushort8v h0 = {(unsigned short)q0.x,(unsigned short)q0.y,(unsigned short)q0.z,(unsigned short)q0.w,
                   (unsigned short)q1.x,(unsigned short)q1.y,(unsigned short)q1.z,(unsigned short)q1.w};
    ushort8v h1 = {(unsigned short)q2.x,(unsigned short)q2.y,(unsigned short)q2.z,(unsigned short)q2.w,
                   (unsigned short)q3.x,(unsigned short)q3.y,(unsigned short)q3.z,(unsigned short)q3.w};
    ushort8v s0 = {(unsigned short)(q0.x>>16),(unsigned short)(q0.y>>16),(unsigned short)(q0.z>>16),(unsigned short)(q0.w>>16),
                   (unsigned short)(q1.x>>16),(unsigned short)(q1.y>>16),(unsigned short)(q1.z>>16),(unsigned short)(q1.w>>16)};
    ushort8v s1 = {(unsigned short)(q2.x>>16),(unsigned short)(q2.y>>16),(unsigned short)(q2.z>>16),(unsigned short)(q2.w>>16),
                   (unsigned short)(q3.x>>16),(unsigned short)(q3.y>>16),(unsigned short)(q3.z>>16),(unsigned short)(q3.w>>16)};
    const int sw = (row & 7) << 4;
    const int hb = row*1024 + seg*32;      // logical byte of h-part
    *(ushort8v*)(Ab + ((hb      ) ^ sw)) = h0;
    *(ushort8v*)(Ab + ((hb + 16 ) ^ sw)) = h1;
    *(ushort8v*)(Ab + ((hb + 512) ^ sw)) = s0;
    *(ushort8v*)(Ab + ((hb + 528) ^ sw)) = s1;
  }
  __syncthreads();

  // ---- r1 via MFMA: wave w owns u in [w*64, w*64+64) ----
  {
    const int lane = tid & 63;
    const int w    = tid >> 6;
    const int nl16 = lane & 15;            // = A row (t), = B col (u_local)
    const int kq   = lane >> 4;
    f32x4 acc[4];
    #pragma unroll
    for (int nt = 0; nt < 4; ++nt) acc[nt] = (f32x4){0.f,0.f,0.f,0.f};
    const int aswz = (nl16 & 7) << 4;
    const unsigned short* wfb = Web + (size_t)w*2048 + lane*8;  // fragment-major base
    #pragma unroll 2
    for (int kc = 0; kc < 16; ++kc){
      const short8 af = *(const short8*)(Ab + ((nl16*1024 + kc*64 + kq*16) ^ aswz));
      const unsigned short* wk = wfb + kc*8192;
      short8 b1[4], b2[4];
      #pragma unroll
      for (int nt = 0; nt < 4; ++nt){
        b1[nt] = *(const short8*)(wk + nt*512);
        b2[nt] = *(const short8*)(wk + 131072 + nt*512);
      }
      #pragma unroll
      for (int nt = 0; nt < 4; ++nt){
        acc[nt] = __builtin_amdgcn_mfma_f32_16x16x32_bf16(af, b1[nt], acc[nt], 0, 0, 0);
        acc[nt] = __builtin_amdgcn_mfma_f32_16x16x32_bf16(af, b2[nt], acc[nt], 0, 0, 0);
      }
    }
    // D layout: col = lane&15 (u_local), row = (lane>>4)*4 + r (t)
    #pragma unroll
    for (int nt = 0; nt < 4; ++nt)
      #pragma unroll
      for (int r = 0; r < 4; ++r)
        Pl[(kq*4 + r)*260 + w*64 + nt*16 + nl16] = __expf(2.0f*acc[nt][r]);
  }

  // ---- e-loop: thread tile = t rows {2tt, 2tt+1} x n cols {tn + 32r} ----
  const int tt = tid >> 5;                 // 0..7
  const int tn = tid & 31;                 // 0..31
  float acc[2][4] = {};
  const float* Qb = Q + (size_t)b * Nsz * Tsz;

  for (int u0 = 0; u0 < Tsz; u0 += 32){
    __syncthreads();                       // prior readers of region done
    #pragma unroll
    for (int i2 = 0; i2 < 4; ++i2){
      const int seg = i2*256 + tid;        // 0..1023
      const int row = seg >> 3;            // 0..127
      const int q   = seg & 7;             // 0..7
      *(float4*)&Qu[row*36 + q*4] = *(const float4*)&Qb[row*256 + u0 + q*4];
    }
    __syncthreads();
    #pragma unroll
    for (int us = 0; us < 8; ++us){
      const int uu = u0 + us*4;
      const float4 ve4 = *(const float4*)&vel[uu];
      const float4 p0  = *(const float4*)&Pl[(2*tt+0)*260 + uu];
      const float4 p1  = *(const float4*)&Pl[(2*tt+1)*260 + uu];
      #pragma unroll
      for (int r = 0; r < 4; ++r){
        const float4 qv = *(const float4*)&Qu[(tn + 32*r)*36 + us*4];
        acc[0][r] = fmaf(ve4.x, rcp_fast(fmaf(p0.x, qv.x, 1.0f)), acc[0][r]);
        acc[0][r] = fmaf(ve4.y, rcp_fast(fmaf(p0.y, qv.y, 1.0f)), acc[0][r]);
        acc[0][r] = fmaf(ve4.z, rcp_fast(fmaf(p0.z, qv.z, 1.0f)), acc[0][r]);
        acc[0][r] = fmaf(ve4.w, rcp_fast(fmaf(p0.w, qv.w, 1.0f)), acc[0][r]);
        acc[1][r] = fmaf(ve4.x, rcp_fast(fmaf(p1.x, qv.x, 1.0f)), acc[1][r]);
        acc[1][r] = fmaf(ve4.y, rcp_fast(fmaf(p1.y, qv.y, 1.0f)), acc[1][r]);
        acc[1][r] = fmaf(ve4.z, rcp_fast(fmaf(p1.z, qv.z, 1.0f)), acc[1][r]);
        acc[1][r] = fmaf(ve4.w, rcp_fast(fmaf(p1.w, qv.w, 1.0f)), acc[1][r]);
      }
    }
  }

  // ---- softmax in registers (row t in one 32-lane group) ----
  float ex[2][4];
  float m0 = -3.0e38f, m1 = -3.0e38f;
  #pragma unroll
  for (int r = 0; r < 4; ++r){
    ex[0][r] = -2.0f * acc[0][r];
    ex[1][r] = -2.0f * acc[1][r];
    m0 = fmaxf(m0, ex[0][r]);
    m1 = fmaxf(m1, ex[1][r]);
  }
  #pragma unroll
  for (int mk = 16; mk >= 1; mk >>= 1){
    m0 = fmaxf(m0, __shfl_xor(m0, mk, 64));
    m1 = fmaxf(m1, __shfl_xor(m1, mk, 64));
  }
  float s0 = 0.0f, s1 = 0.0f;
  #pragma unroll
  for (int r = 0; r < 4; ++r){
    const float p0 = __expf(ex[0][r] - m0);
    const float p1 = __expf(ex[1][r] - m1);
    ex[0][r] = p0; ex[1][r] = p1;
    s0 += p0; s1 += p1;
  }
  #pragma unroll
  for (int mk = 16; mk >= 1; mk >>= 1){
    s0 += __shfl_xor(s0, mk, 64);
    s1 += __shfl_xor(s1, mk, 64);
  }
  const float inv0 = rcp_fast(s0);
  const float inv1 = rcp_fast(s1);

  #pragma unroll
  for (int r = 0; r < 4; ++r){
    const size_t i0 = ((size_t)b*Tsz + t0 + 2*tt + 0)*Nsz + tn + 32*r;
    const size_t i1 = ((size_t)b*Tsz + t0 + 2*tt + 1)*Nsz + tn + 32*r;
    out[i0] = ex[0][r] * inv0 * x[i0];
    out[i1] = ex[1][r] * inv1 * x[i1];
  }
}

// ---------------------------------------------------------------------------
extern "C" void kernel_launch(void* const* d_in, const int* in_sizes, int n_in,
                              void* d_out, int out_size, void* d_ws, size_t ws_size,
                              hipStream_t stream){
  const float* x    = (const float*)d_in[0];
  const float* s_in = (const float*)d_in[1];
  const float* h_in = (const float*)d_in[2];
  const float* We   = (const float*)d_in[3];
  const float* Ue   = (const float*)d_in[4];
  const float* ve   = (const float*)d_in[5];
  const float* Wk   = (const float*)d_in[6];
  const float* Wr   = (const float*)d_in[7];
  const float* bias = (const float*)d_in[8];
  float* out = (float*)d_out;

  // ws layout (~201.9 MB): Q fp32 67MB | HS 134MB | ctr 32KB | Web 512KB
  float* Q = (float*)d_ws;
  unsigned short* HS = (unsigned short*)(Q + (size_t)Bsz*Nsz*Tsz);
  int* ctr = (int*)(HS + (size_t)Tsz*Bsz*512);
  unsigned short* Web = (unsigned short*)(ctr + 8192);

  k_init<<<(Bsz*Msz)/256, 256, 0, stream>>>(h_in, s_in, We, HS, ctr, Web);
  k_r2exp<<<dim3(Bsz, 8), 256, 0, stream>>>(x, Ue, Q);
  k_scan<<<128, 256, 0, stream>>>(x, Wk, Wr, bias, s_in, HS, ctr);
  k_attn<<<dim3(Bsz, Tsz/16), 256, 0, stream>>>(HS, Q, Web, ve, x, out);
}

// Round 8
// 1419.847 us; speedup vs baseline: 1.2615x; 1.1286x over previous
//
#include <hip/hip_runtime.h>

static constexpr int Bsz = 512;
static constexpr int Tsz = 256;
static constexpr int Nsz = 128;
static constexpr int Msz = 256;

using short8  = __attribute__((ext_vector_type(8))) short;
using ushort8v= __attribute__((ext_vector_type(8))) unsigned short;
using f32x4   = __attribute__((ext_vector_type(4))) float;

__device__ __forceinline__ float rcp_fast(float v){ return __builtin_amdgcn_rcpf(v); }
__device__ __forceinline__ float sigmoid_fast(float v){ return rcp_fast(1.0f + __expf(-v)); }
__device__ __forceinline__ float tanh_fast(float v){ return 1.0f - 2.0f * rcp_fast(1.0f + __expf(2.0f * v)); }
__device__ __forceinline__ unsigned short bf16r(float f){
  unsigned u = __float_as_uint(f);
  u += 0x7FFFu + ((u >> 16) & 1u);
  return (unsigned short)(u >> 16);
}

// ---------------------------------------------------------------------------
// HS layout (unit-interleaved): HS[t][b] = 256 uints; uint[u] = h|s<<16.
// Written sc0 sc1 (write-through to MALL) by k_scan; read sc0 sc1 in-loop.
// Web layout (FRAGMENT-MAJOR):
//   idx(kc,w,nt,lane,j) = kc*8192 + w*2048 + nt*512 + lane*8 + j
//   value = bf16hi(We[kc*32 + (lane>>4)*8 + j][w*64 + nt*16 + (lane&15)])
//   residual table at +131072 shorts. A wave's B-fragment load is
//   base + lane*16B: ONE coalesced 1KB transaction (L2-resident).
// ---------------------------------------------------------------------------

// K0: HS slab t=0 + zero scan counters + We -> fragment-major bf16-hi/res.
__global__ __launch_bounds__(256) void k_init(const float* __restrict__ h_in,
                                              const float* __restrict__ s_in,
                                              const float* __restrict__ We,
                                              unsigned short* __restrict__ HS,
                                              int* __restrict__ ctr,
                                              unsigned short* __restrict__ Web){
  const int i = blockIdx.x * 256 + threadIdx.x;   // 0 .. B*M-1 (131072)
  if (i < 8192) ctr[i] = 0;
  const float h = h_in[i];
  const float s = s_in[i];
  const int b = i >> 8;
  const int m = i & 255;
  unsigned* row = (unsigned*)(HS + (size_t)b * 512);
  row[m] = (unsigned)bf16r(h) | ((unsigned)bf16r(s) << 16);
  // dest-major Wf build: coalesced writes, gather-reads from L2-cached We
  const int j    = i & 7;
  const int lane = (i >> 3) & 63;
  const int nt   = (i >> 9) & 3;
  const int w    = (i >> 11) & 3;
  const int kc   = (i >> 13) & 15;
  const int kq   = lane >> 4;
  const int nl16 = lane & 15;
  const int k = kc*32 + kq*8 + j;          // 0..511
  const int u = w*64 + nt*16 + nl16;       // 0..255
  const float wv = We[(size_t)k*256 + u];
  const unsigned short hi = bf16r(wv);
  const float res = wv - __uint_as_float((unsigned)hi << 16);
  Web[i]          = hi;
  Web[131072 + i] = bf16r(res);
}

// ---------------------------------------------------------------------------
// K1: Q[b][n][u] = exp( 2 * sum_t x[b][t][n] * Ue[t][u] )   (r2, pre-exp'd)
// ---------------------------------------------------------------------------
__global__ __launch_bounds__(256) void k_r2exp(const float* __restrict__ x,
                                               const float* __restrict__ Ue,
                                               float* __restrict__ Q){
  const int b  = blockIdx.x;
  const int n0 = (blockIdx.y >> 2) * 64;
  const int u0 = (blockIdx.y & 3) * 64;
  __shared__ float Al[16][68];
  __shared__ float Bl[16][68];
  const int tid  = threadIdx.x;
  const int lane = tid & 63;
  const int kq   = tid >> 6;
  const int ty   = tid >> 4;
  const int tx   = tid & 15;
  float acc[4][4] = {};
  const float* xb = x + (size_t)b * Tsz * Nsz;
  for (int k0 = 0; k0 < Tsz; k0 += 16){
    #pragma unroll
    for (int i = 0; i < 4; ++i){
      const int k = kq*4 + i;
      Al[k][lane] = xb[(size_t)(k0+k)*Nsz + n0 + lane];
      Bl[k][lane] = Ue[(size_t)(k0+k)*Tsz + u0 + lane];
    }
    __syncthreads();
    #pragma unroll
    for (int kk = 0; kk < 16; ++kk){
      const float4 a = *(const float4*)&Al[kk][ty*4];
      const float4 w = *(const float4*)&Bl[kk][tx*4];
      const float av[4] = {a.x,a.y,a.z,a.w};
      const float wv[4] = {w.x,w.y,w.z,w.w};
      #pragma unroll
      for (int i=0;i<4;++i)
        #pragma unroll
        for (int j=0;j<4;++j)
          acc[i][j] = fmaf(av[i], wv[j], acc[i][j]);
    }
    __syncthreads();
  }
  float* Qb = Q + (size_t)b * Nsz * Tsz;
  #pragma unroll
  for (int i=0;i<4;++i){
    float4 v;
    v.x = __expf(2.0f*acc[i][0]);
    v.y = __expf(2.0f*acc[i][1]);
    v.z = __expf(2.0f*acc[i][2]);
    v.w = __expf(2.0f*acc[i][3]);
    *(float4*)&Qb[(size_t)(n0 + ty*4 + i)*Tsz + u0 + tx*4] = v;
  }
}

// ---------------------------------------------------------------------------
// K2: persistent LSTM scan, v4 (unchanged — zero cache-maintenance sync;
// sc0 sc1 write-through HS, relaxed flags).
// ---------------------------------------------------------------------------
__global__ __launch_bounds__(256, 1) void k_scan(const float* __restrict__ x,
                                                 const float* __restrict__ Wk,
                                                 const float* __restrict__ Wr,
                                                 const float* __restrict__ bias,
                                                 const float* __restrict__ s_in,
                                                 unsigned short* __restrict__ HS,
                                                 int* __restrict__ ctr){
  const int bgq = blockIdx.x & 31;    // batch group 0..31 (16 batches)
  const int ug  = blockIdx.x >> 5;    // unit group 0..3 (64 units)
  const int b0  = bgq * 16;
  const int u0  = ug * 64;
  const int tid  = threadIdx.x;
  const int w    = tid >> 6;          // wave 0..3 -> units u0+16w..
  const int lane = tid & 63;
  const int nl   = lane & 15;
  const int kq   = lane >> 4;

  __shared__ unsigned short Xa[4*16*32];   // x_t chunks (k=0..127),   4 KB
  __shared__ unsigned short Ha[8*16*32];   // h_t chunks (k=128..383), 8 KB

  const int ucol = u0 + (w<<4) + nl;       // this lane's unit column

  // ---- preload W fragments (bf16) into registers: 12 chunks x 4 gates ----
  short8 wf[12][4];
  #pragma unroll
  for (int c = 0; c < 12; ++c){
    #pragma unroll
    for (int g = 0; g < 4; ++g){
      const int jcol = g*Msz + ucol;
      short8 f;
      #pragma unroll
      for (int j = 0; j < 8; ++j){
        const int k = c*32 + kq*8 + j;
        const float wv = (k < Nsz) ? Wk[(size_t)k*(4*Msz) + jcol]
                                   : Wr[(size_t)(k - Nsz)*(4*Msz) + jcol];
        f[j] = (short)bf16r(wv);
      }
      wf[c][g] = f;
    }
  }

  // ---- per-lane state: 4 batch rows x 1 unit ----
  const int r0 = kq*4;                     // first of 4 batch rows (C layout)
  float bi[4];
  #pragma unroll
  for (int g = 0; g < 4; ++g) bi[g] = bias[g*Msz + ucol];
  float s_reg[4];
  #pragma unroll
  for (int r = 0; r < 4; ++r)
    s_reg[r] = s_in[(size_t)(b0 + r0 + r)*Msz + ucol];

  // staging indices (256 threads cover 16 rows x full width)
  const int srow = tid >> 4;               // 0..15
  const int sx_n = (tid & 15) * 8;         // x col base (8 fp32)
  const int sh_m = (tid & 15) * 16;        // h col base (16 units)
  const int arow = nl*32 + kq*8;           // A-fragment LDS offset (shorts)

  #pragma unroll 1
  for (int t = 0; t < Tsz - 1; ++t){
    // ---- stage x_t (no dependence on the group barrier) ----
    {
      const float* xp = x + ((size_t)(b0+srow)*Tsz + t)*Nsz + sx_n;
      const float4 v0 = *(const float4*)(xp);
      const float4 v1 = *(const float4*)(xp + 4);
      ushort4 o0, o1;
      o0.x = bf16r(v0.x); o0.y = bf16r(v0.y); o0.z = bf16r(v0.z); o0.w = bf16r(v0.w);
      o1.x = bf16r(v1.x); o1.y = bf16r(v1.y); o1.z = bf16r(v1.z); o1.w = bf16r(v1.w);
      const int base = (sx_n>>5)*512 + srow*32 + (sx_n & 31);
      *(ushort4*)&Xa[base]     = o0;
      *(ushort4*)&Xa[base + 4] = o1;
    }
    __syncthreads();   // Xa ready

    // ---- x_t @ Wk : chunks 0..3 (overlaps producers still finishing h_t) ----
    f32x4 acc0 = {0.f,0.f,0.f,0.f}, acc1 = {0.f,0.f,0.f,0.f};
    f32x4 acc2 = {0.f,0.f,0.f,0.f}, acc3 = {0.f,0.f,0.f,0.f};
    #pragma unroll
    for (int c = 0; c < 4; ++c){
      const short8 af = *(const short8*)&Xa[c*512 + arow];
      acc0 = __builtin_amdgcn_mfma_f32_16x16x32_bf16(af, wf[c][0], acc0, 0, 0, 0);
      acc1 = __builtin_amdgcn_mfma_f32_16x16x32_bf16(af, wf[c][1], acc1, 0, 0, 0);
      acc2 = __builtin_amdgcn_mfma_f32_16x16x32_bf16(af, wf[c][2], acc2, 0, 0, 0);
      acc3 = __builtin_amdgcn_mfma_f32_16x16x32_bf16(af, wf[c][3], acc3, 0, 0, 0);
    }

    // ---- wait for h_t: tid0 relaxed spin (no cache ops), then barrier ----
    if (t > 0){
      if (tid == 0){
        int* cp = &ctr[(t-1)*32 + bgq];
        while (__hip_atomic_load(cp, __ATOMIC_RELAXED, __HIP_MEMORY_SCOPE_AGENT) < 4)
          __builtin_amdgcn_s_sleep(1);
      }
      __syncthreads();
    }

    // ---- stage h_t: sc0 sc1 loads (MALL-coherent), extract h (low16) ----
    {
      const unsigned* hp = (const unsigned*)(HS + ((size_t)t*Bsz + b0 + srow)*512) + sh_m;
      uint4 a0, a1, a2, a3;
      asm volatile(
        "global_load_dwordx4 %0, %4, off sc0 sc1\n\t"
        "global_load_dwordx4 %1, %4, off offset:16 sc0 sc1\n\t"
        "global_load_dwordx4 %2, %4, off offset:32 sc0 sc1\n\t"
        "global_load_dwordx4 %3, %4, off offset:48 sc0 sc1\n\t"
        "s_waitcnt vmcnt(0)"
        : "=&v"(a0), "=&v"(a1), "=&v"(a2), "=&v"(a3)
        : "v"(hp)
        : "memory");
      ushort4 h0, h1, h2, h3;
      h0.x=(unsigned short)a0.x; h0.y=(unsigned short)a0.y; h0.z=(unsigned short)a0.z; h0.w=(unsigned short)a0.w;
      h1.x=(unsigned short)a1.x; h1.y=(unsigned short)a1.y; h1.z=(unsigned short)a1.z; h1.w=(unsigned short)a1.w;
      h2.x=(unsigned short)a2.x; h2.y=(unsigned short)a2.y; h2.z=(unsigned short)a2.z; h2.w=(unsigned short)a2.w;
      h3.x=(unsigned short)a3.x; h3.y=(unsigned short)a3.y; h3.z=(unsigned short)a3.z; h3.w=(unsigned short)a3.w;
      const int base = (sh_m>>5)*512 + srow*32 + (sh_m & 31);
      *(ushort4*)&Ha[base +  0] = h0;
      *(ushort4*)&Ha[base +  4] = h1;
      *(ushort4*)&Ha[base +  8] = h2;
      *(ushort4*)&Ha[base + 12] = h3;
    }
    __syncthreads();   // Ha ready

    // ---- h_t @ Wr : chunks 4..11 ----
    #pragma unroll
    for (int c = 0; c < 8; ++c){
      const short8 af = *(const short8*)&Ha[c*512 + arow];
      acc0 = __builtin_amdgcn_mfma_f32_16x16x32_bf16(af, wf[c+4][0], acc0, 0, 0, 0);
      acc1 = __builtin_amdgcn_mfma_f32_16x16x32_bf16(af, wf[c+4][1], acc1, 0, 0, 0);
      acc2 = __builtin_amdgcn_mfma_f32_16x16x32_bf16(af, wf[c+4][2], acc2, 0, 0, 0);
      acc3 = __builtin_amdgcn_mfma_f32_16x16x32_bf16(af, wf[c+4][3], acc3, 0, 0, 0);
    }

    // ---- gate update; pack (h,s) per unit; sc0 sc1 write-through stores ----
    {
      unsigned hv[4];
      #pragma unroll
      for (int r = 0; r < 4; ++r){
        const float ig = sigmoid_fast(acc0[r] + bi[0]);
        const float fg = sigmoid_fast(acc1[r] + bi[1]);
        const float gg = tanh_fast  (acc2[r] + bi[2]);
        const float og = sigmoid_fast(acc3[r] + bi[3]);
        const float s1 = fmaf(fg, s_reg[r], ig * gg);
        s_reg[r] = s1;
        const float hn = og * tanh_fast(s1);
        hv[r] = (unsigned)bf16r(hn) | ((unsigned)bf16r(s1) << 16);
      }
      unsigned* gp = (unsigned*)(HS + ((size_t)(t+1)*Bsz + b0 + r0)*512) + ucol;
      asm volatile(
        "global_store_dword %0, %1, off sc0 sc1\n\t"
        "global_store_dword %0, %2, off offset:1024 sc0 sc1\n\t"
        "global_store_dword %0, %3, off offset:2048 sc0 sc1\n\t"
        "global_store_dword %0, %4, off offset:3072 sc0 sc1\n\t"
        "s_waitcnt vmcnt(0)"
        :: "v"(gp), "v"(hv[0]), "v"(hv[1]), "v"(hv[2]), "v"(hv[3])
        : "memory");
    }

    // ---- publish: stores already at MALL -> relaxed flag add ----
    __syncthreads();
    if (tid == 0)
      __hip_atomic_fetch_add(&ctr[t*32 + bgq], 1, __ATOMIC_RELAXED,
                             __HIP_MEMORY_SCOPE_AGENT);
  }
}

// ---------------------------------------------------------------------------
// K3: attention v6 — identical to v5 except the VGPR cap is lifted
// (__launch_bounds__(256), was (256,4)): R5's 64-VGPR cap caused scratch
// spilling (WRITE_SIZE 866 MB vs 67 MB ideal). LDS (36.4 KB) still allows
// 4 blocks/CU when the compiler lands <=128 VGPR.
// ---------------------------------------------------------------------------
__global__ __launch_bounds__(256) void k_attn(const unsigned short* __restrict__ HS,
                                              const float* __restrict__ Q,
                                              const unsigned short* __restrict__ Web,
                                              const float* __restrict__ ve,
                                              const float* __restrict__ x,
                                              float* __restrict__ out){
  const unsigned wgid = blockIdx.x + (blockIdx.y << 9);
  const unsigned l    = ((wgid & 7u) << 10) + (wgid >> 3);
  const int b  = (int)(l >> 4);
  const int t0 = (int)(l & 15u) << 4;

  __shared__ __align__(16) char smem[36096];
  float* Pl  = (float*)smem;               // [16][260] fp32
  char*  Ab  = smem + 16640;               // Al: [16][512] bf16 swizzled (phase 1)
  float* Qu  = (float*)(smem + 16640);     // [128][36] fp32 (phase 2, aliases Al)
  float* vel = (float*)(smem + 35072);     // [256]

  const int tid = threadIdx.x;
  vel[tid] = ve[tid];

  // ---- stage packed HS -> Al bf16 [16][512], XOR-swizzle ((row&7)<<4) ----
  {
    const int row = tid >> 4;
    const int seg = tid & 15;
    const uint4* src = (const uint4*)((const unsigned*)(HS + ((size_t)(t0 + row)*Bsz + b)*512) + seg*16);
    const uint4 q0 = src[0], q1 = src[1], q2 = src[2], q3 = src[3];
    ushort8v h0 = {(unsigned short)q0.x,(unsigned short)q0.y,(unsigned short)q0.z,(unsigned short)q0.w,
                   (unsigned short)q1.x,(unsigned short)q1.y,(unsigned short)q1.z,(unsigned short)q1.w};
    ushort8v h1 = {(unsigned short)q2.x,(unsigned short)q2.y,(unsigned short)q2.z,(unsigned short)q2.w,
                   (unsigned short)q3.x,(unsigned short)q3.y,(unsigned short)q3.z,(unsigned short)q3.w};
    ushort8v s0 = {(unsigned short)(q0.x>>16),(unsigned short)(q0.y>>16),(unsigned short)(q0.z>>16),(unsigned short)(q0.w>>16),
                   (unsigned short)(q1.x>>16),(unsigned short)(q1.y>>16),(unsigned short)(q1.z>>16),(unsigned short)(q1.w>>16)};
    ushort8v s1 = {(unsigned short)(q2.x>>16),(unsigned short)(q2.y>>16),(unsigned short)(q2.z>>16),(unsigned short)(q2.w>>16),
                   (unsigned short)(q3.x>>16),(unsigned short)(q3.y>>16),(unsigned short)(q3.z>>16),(unsigned short)(q3.w>>16)};
    const int sw = (row & 7) << 4;
    const int hb = row*1024 + seg*32;      // logical byte of h-part
    *(ushort8v*)(Ab + ((hb      ) ^ sw)) = h0;
    *(ushort8v*)(Ab + ((hb + 16 ) ^ sw)) = h1;
    *(ushort8v*)(Ab + ((hb + 512) ^ sw)) = s0;
    *(ushort8v*)(Ab + ((hb + 528) ^ sw)) = s1;
  }
  __syncthreads();

  // ---- r1 via MFMA: wave w owns u in [w*64, w*64+64) ----
  {
    const int lane = tid & 63;
    const int w    = tid >> 6;
    const int nl16 = lane & 15;            // = A row (t), = B col (u_local)
    const int kq   = lane >> 4;
    f32x4 acc[4];
    #pragma unroll
    for (int nt = 0; nt < 4; ++nt) acc[nt] = (f32x4){0.f,0.f,0.f,0.f};
    const int aswz = (nl16 & 7) << 4;
    const unsigned short* wfb = Web + (size_t)w*2048 + lane*8;  // fragment-major base
    #pragma unroll 2
    for (int kc = 0; kc < 16; ++kc){
      const short8 af = *(const short8*)(Ab + ((nl16*1024 + kc*64 + kq*16) ^ aswz));
      const unsigned short* wk = wfb + kc*8192;
      short8 b1[4], b2[4];
      #pragma unroll
      for (int nt = 0; nt < 4; ++nt){
        b1[nt] = *(const short8*)(wk + nt*512);
        b2[nt] = *(const short8*)(wk + 131072 + nt*512);
      }
      #pragma unroll
      for (int nt = 0; nt < 4; ++nt){
        acc[nt] = __builtin_amdgcn_mfma_f32_16x16x32_bf16(af, b1[nt], acc[nt], 0, 0, 0);
        acc[nt] = __builtin_amdgcn_mfma_f32_16x16x32_bf16(af, b2[nt], acc[nt], 0, 0, 0);
      }
    }
    // D layout: col = lane&15 (u_local), row = (lane>>4)*4 + r (t)
    #pragma unroll
    for (int nt = 0; nt < 4; ++nt)
      #pragma unroll
      for (int r = 0; r < 4; ++r)
        Pl[(kq*4 + r)*260 + w*64 + nt*16 + nl16] = __expf(2.0f*acc[nt][r]);
  }

  // ---- e-loop: thread tile = t rows {2tt, 2tt+1} x n cols {tn + 32r} ----
  const int tt = tid >> 5;                 // 0..7
  const int tn = tid & 31;                 // 0..31
  float acc[2][4] = {};
  const float* Qb = Q + (size_t)b * Nsz * Tsz;

  for (int u0 = 0; u0 < Tsz; u0 += 32){
    __syncthreads();                       // prior readers of region done
    #pragma unroll
    for (int i2 = 0; i2 < 4; ++i2){
      const int seg = i2*256 + tid;        // 0..1023
      const int row = seg >> 3;            // 0..127
      const int q   = seg & 7;             // 0..7
      *(float4*)&Qu[row*36 + q*4] = *(const float4*)&Qb[row*256 + u0 + q*4];
    }
    __syncthreads();
    #pragma unroll
    for (int us = 0; us < 8; ++us){
      const int uu = u0 + us*4;
      const float4 ve4 = *(const float4*)&vel[uu];
      const float4 p0  = *(const float4*)&Pl[(2*tt+0)*260 + uu];
      const float4 p1  = *(const float4*)&Pl[(2*tt+1)*260 + uu];
      #pragma unroll
      for (int r = 0; r < 4; ++r){
        const float4 qv = *(const float4*)&Qu[(tn + 32*r)*36 + us*4];
        acc[0][r] = fmaf(ve4.x, rcp_fast(fmaf(p0.x, qv.x, 1.0f)), acc[0][r]);
        acc[0][r] = fmaf(ve4.y, rcp_fast(fmaf(p0.y, qv.y, 1.0f)), acc[0][r]);
        acc[0][r] = fmaf(ve4.z, rcp_fast(fmaf(p0.z, qv.z, 1.0f)), acc[0][r]);
        acc[0][r] = fmaf(ve4.w, rcp_fast(fmaf(p0.w, qv.w, 1.0f)), acc[0][r]);
        acc[1][r] = fmaf(ve4.x, rcp_fast(fmaf(p1.x, qv.x, 1.0f)), acc[1][r]);
        acc[1][r] = fmaf(ve4.y, rcp_fast(fmaf(p1.y, qv.y, 1.0f)), acc[1][r]);
        acc[1][r] = fmaf(ve4.z, rcp_fast(fmaf(p1.z, qv.z, 1.0f)), acc[1][r]);
        acc[1][r] = fmaf(ve4.w, rcp_fast(fmaf(p1.w, qv.w, 1.0f)), acc[1][r]);
      }
    }
  }

  // ---- softmax in registers (row t in one 32-lane group) ----
  float ex[2][4];
  float m0 = -3.0e38f, m1 = -3.0e38f;
  #pragma unroll
  for (int r = 0; r < 4; ++r){
    ex[0][r] = -2.0f * acc[0][r];
    ex[1][r] = -2.0f * acc[1][r];
    m0 = fmaxf(m0, ex[0][r]);
    m1 = fmaxf(m1, ex[1][r]);
  }
  #pragma unroll
  for (int mk = 16; mk >= 1; mk >>= 1){
    m0 = fmaxf(m0, __shfl_xor(m0, mk, 64));
    m1 = fmaxf(m1, __shfl_xor(m1, mk, 64));
  }
  float s0 = 0.0f, s1 = 0.0f;
  #pragma unroll
  for (int r = 0; r < 4; ++r){
    const float p0 = __expf(ex[0][r] - m0);
    const float p1 = __expf(ex[1][r] - m1);
    ex[0][r] = p0; ex[1][r] = p1;
    s0 += p0; s1 += p1;
  }
  #pragma unroll
  for (int mk = 16; mk >= 1; mk >>= 1){
    s0 += __shfl_xor(s0, mk, 64);
    s1 += __shfl_xor(s1, mk, 64);
  }
  const float inv0 = rcp_fast(s0);
  const float inv1 = rcp_fast(s1);

  #pragma unroll
  for (int r = 0; r < 4; ++r){
    const size_t i0 = ((size_t)b*Tsz + t0 + 2*tt + 0)*Nsz + tn + 32*r;
    const size_t i1 = ((size_t)b*Tsz + t0 + 2*tt + 1)*Nsz + tn + 32*r;
    out[i0] = ex[0][r] * inv0 * x[i0];
    out[i1] = ex[1][r] * inv1 * x[i1];
  }
}

// ---------------------------------------------------------------------------
extern "C" void kernel_launch(void* const* d_in, const int* in_sizes, int n_in,
                              void* d_out, int out_size, void* d_ws, size_t ws_size,
                              hipStream_t stream){
  const float* x    = (const float*)d_in[0];
  const float* s_in = (const float*)d_in[1];
  const float* h_in = (const float*)d_in[2];
  const float* We   = (const float*)d_in[3];
  const float* Ue   = (const float*)d_in[4];
  const float* ve   = (const float*)d_in[5];
  const float* Wk   = (const float*)d_in[6];
  const float* Wr   = (const float*)d_in[7];
  const float* bias = (const float*)d_in[8];
  float* out = (float*)d_out;

  // ws layout (~201.9 MB): Q fp32 67MB | HS 134MB | ctr 32KB | Web 512KB
  float* Q = (float*)d_ws;
  unsigned short* HS = (unsigned short*)(Q + (size_t)Bsz*Nsz*Tsz);
  int* ctr = (int*)(HS + (size_t)Tsz*Bsz*512);
  unsigned short* Web = (unsigned short*)(ctr + 8192);

  k_init<<<(Bsz*Msz)/256, 256, 0, stream>>>(h_in, s_in, We, HS, ctr, Web);
  k_r2exp<<<dim3(Bsz, 8), 256, 0, stream>>>(x, Ue, Q);
  k_scan<<<128, 256, 0, stream>>>(x, Wk, Wr, bias, s_in, HS, ctr);
  k_attn<<<dim3(Bsz, Tsz/16), 256, 0, stream>>>(HS, Q, Web, ve, x, out);
}